// Round 5
// baseline (823.186 us; speedup 1.0000x reference)
//
#include <hip/hip_runtime.h>
#include <hip/hip_cooperative_groups.h>
#include <math.h>

namespace cg = cooperative_groups;

#define BB 32
#define MM 2048
#define KK 4
#define EE 128
#define GG 128
#define VV 50000
#define HOPS 3
#define NT 391    // ceil(VV/128) v-tiles

struct Args {
    const int*   ctx;
    const float* hprev;
    const int*   y;
    const float* emb;
    const float* W_ih;
    const float* W_hh;
    const float* b_ih;
    const float* b_hh;
    const float* Wv;
    const float* bv;
    float* out_h;
    float* out_pv;
    float* out_attn;
    float* q0;      // [B][E]   GRU hidden (== h output)
    float* o1s;     // [B][E]   snapshot of o after hop 0
    float* part;    // [B][8][2] vocab softmax partials
    float* d;       // [B][V]   per-vocab dot with query
    float* w;       // [B][V]   scattered attention weights (o_acc contiguous after)
    float* o_acc;   // [B][E]   accumulated memory reads (w + B*V)
    int nb;
};

__global__ __launch_bounds__(256, 2) void fused_kernel(Args a) {
    cg::grid_group grid = cg::this_grid();
    const int blk  = blockIdx.x;
    const int t    = threadIdx.x;
    const int nb   = a.nb;
    const int lane = t & 63;
    const int wvid = t >> 6;

    __shared__ __align__(16) float smem[12352];   // 49.4 KB, aliased per phase

    // ================= P0: GRU (blocks 0..31) + zero w,o_acc (rest) =================
    if (blk < BB) {
        int b = blk;
        float* x  = smem;          // 128
        float* hh = smem + 128;    // 128
        float* gi = smem + 256;    // 384
        float* gh = smem + 640;    // 384
        if (t < EE)          x[t]     = a.emb[(size_t)a.y[b]*EE + t];
        else if (t < 2*EE)   hh[t-EE] = a.hprev[b*GG + (t-EE)];
        __syncthreads();
        for (int g = t; g < 3*GG; g += 256) {
            float accI = a.b_ih[g], accH = a.b_hh[g];
            const float* wi = a.W_ih + (size_t)g*EE;
            const float* wh = a.W_hh + (size_t)g*GG;
            #pragma unroll 8
            for (int e = 0; e < EE; e++) { accI += x[e]*wi[e]; accH += hh[e]*wh[e]; }
            gi[g] = accI; gh[g] = accH;
        }
        __syncthreads();
        if (t < GG) {
            float r = 1.f/(1.f + __expf(-(gi[t]      + gh[t])));
            float z = 1.f/(1.f + __expf(-(gi[GG+t]   + gh[GG+t])));
            float n = tanhf(gi[2*GG+t] + r*gh[2*GG+t]);
            float hn = (1.f - z)*n + z*hh[t];
            a.out_h[b*GG + t] = hn;
            a.q0[b*GG + t]    = hn;
        }
    } else {
        // zero w[B][V] and o_acc[B][E] (contiguous)
        const int total4 = (BB*VV + BB*EE)/4;
        float4* wz = (float4*)a.w;
        for (int i = (blk-BB)*256 + t; i < total4; i += (nb-BB)*256)
            wz[i] = make_float4(0.f,0.f,0.f,0.f);
    }
    grid.sync();

    // ================= hops =================
    for (int hop = 0; hop < HOPS; hop++) {
        const int last = (hop == HOPS-1);

        // ---- P1: d[b][v] = (q0[b]+o_acc[b]) . T[v]  (wave-uniform skinny GEMM) ----
        {
            const float* T = a.emb + (size_t)hop*VV*EE;
            float* Us = smem;          // [128][32]
            float* Wt = smem + 4096;   // [32][130]
            for (int tile = blk; tile < NT; tile += nb) {
                __syncthreads();   // guard Us restage vs previous tile's readers
                for (int i = t; i < 128*32; i += 256) {
                    int e = i >> 5, b = i & 31;
                    Us[i] = a.q0[b*EE + e] + a.o_acc[b*EE + e];
                }
                int v0 = tile * 128;
                float acc[2][8];
                #pragma unroll
                for (int i = 0; i < 2; i++)
                    #pragma unroll
                    for (int j = 0; j < 8; j++) acc[i][j] = 0.f;

                for (int ec = 0; ec < 128; ec += 32) {
                    __syncthreads();
                    #pragma unroll
                    for (int j = 0; j < 4; j++) {
                        int f = t + j*256;
                        int row = f >> 3, c4 = f & 7;
                        float4 w4 = make_float4(0.f,0.f,0.f,0.f);
                        if (v0 + row < VV) w4 = *(const float4*)(T + (size_t)(v0+row)*EE + ec + c4*4);
                        Wt[(c4*4+0)*130 + row] = w4.x;
                        Wt[(c4*4+1)*130 + row] = w4.y;
                        Wt[(c4*4+2)*130 + row] = w4.z;
                        Wt[(c4*4+3)*130 + row] = w4.w;
                    }
                    __syncthreads();
                    #pragma unroll 8
                    for (int e = 0; e < 32; e++) {
                        float2 w2 = *(const float2*)(Wt + e*130 + lane*2);
                        float4 ua = *(const float4*)(Us + (ec+e)*32 + wvid*8);
                        float4 ub = *(const float4*)(Us + (ec+e)*32 + wvid*8 + 4);
                        acc[0][0] += w2.x*ua.x; acc[1][0] += w2.y*ua.x;
                        acc[0][1] += w2.x*ua.y; acc[1][1] += w2.y*ua.y;
                        acc[0][2] += w2.x*ua.z; acc[1][2] += w2.y*ua.z;
                        acc[0][3] += w2.x*ua.w; acc[1][3] += w2.y*ua.w;
                        acc[0][4] += w2.x*ub.x; acc[1][4] += w2.y*ub.x;
                        acc[0][5] += w2.x*ub.y; acc[1][5] += w2.y*ub.y;
                        acc[0][6] += w2.x*ub.z; acc[1][6] += w2.y*ub.z;
                        acc[0][7] += w2.x*ub.w; acc[1][7] += w2.y*ub.w;
                    }
                }
                int v = v0 + lane*2;
                if (v < VV) {
                    #pragma unroll
                    for (int j = 0; j < 8; j++) {
                        float2 r; r.x = acc[0][j]; r.y = acc[1][j];
                        *(float2*)(a.d + (size_t)(wvid*8 + j)*VV + v) = r;
                    }
                }
            }
            // duty work (tail blocks, tile-free when nb=512): before hop1's scatter,
            // snapshot o1 = o_acc (== o from hop0) and re-zero w
            if (hop == 1 && blk >= nb-64) {
                int base = (blk-(nb-64))*256 + t;
                float4* wz = (float4*)a.w;
                for (int i = base; i < (BB*VV)/4; i += 64*256)
                    wz[i] = make_float4(0.f,0.f,0.f,0.f);
                for (int i = base; i < BB*EE; i += 64*256)
                    a.o1s[i] = a.o_acc[i];
            }
        }
        grid.sync();

        // ---- P2: gather + softmax over M + scatter/output (blocks 0..31) ----
        if (blk < BB) {
            int b = blk;
            const float* db = a.d + (size_t)b*VV;
            const int4* cb  = (const int4*)a.ctx + b*MM;
            float pv[8];
            float mx = -INFINITY;
            #pragma unroll
            for (int i = 0; i < 8; i++) {
                int m = t + i*256;
                int4 c = cb[m];
                pv[i] = db[c.x] + db[c.y] + db[c.z] + db[c.w];
                mx = fmaxf(mx, pv[i]);
            }
            float* red = smem;
            #pragma unroll
            for (int off = 32; off; off >>= 1) mx = fmaxf(mx, __shfl_down(mx, off));
            if (lane == 0) red[wvid] = mx;
            __syncthreads();
            if (t == 0) red[4] = fmaxf(fmaxf(red[0],red[1]), fmaxf(red[2],red[3]));
            __syncthreads();
            mx = red[4];
            float sum = 0.f;
            #pragma unroll
            for (int i = 0; i < 8; i++) { pv[i] = __expf(pv[i] - mx); sum += pv[i]; }
            #pragma unroll
            for (int off = 32; off; off >>= 1) sum += __shfl_down(sum, off);
            if (lane == 0) red[8 + wvid] = sum;
            __syncthreads();
            if (t == 0) red[13] = 1.f / (red[8]+red[9]+red[10]+red[11]);
            __syncthreads();
            float rs = red[13];
            if (last) {
                #pragma unroll
                for (int i = 0; i < 8; i++)
                    a.out_attn[b*MM + t + i*256] = pv[i]*rs;
            } else {
                float* wb = a.w + (size_t)b*VV;
                #pragma unroll
                for (int i = 0; i < 8; i++) {
                    float av = pv[i]*rs;
                    int4 c = cb[t + i*256];
                    atomicAdd(wb + c.x, av);
                    atomicAdd(wb + c.y, av);
                    atomicAdd(wb + c.z, av);
                    atomicAdd(wb + c.w, av);
                }
            }
        }
        grid.sync();

        // ---- P3: o_acc[b][e] += sum_v w[b][v] * T2[v][e] ----
        if (!last) {
            const float* T2 = a.emb + (size_t)(hop+1)*VV*EE;
            float* embS = smem;          // [64][128]
            float* wS   = smem + 8192;   // [64][32]
            float av[8][2];
            #pragma unroll
            for (int j = 0; j < 8; j++) { av[j][0] = 0.f; av[j][1] = 0.f; }
            for (int chunk = blk; chunk < NT; chunk += nb) {
                int v0 = chunk*128, vend = min(v0+128, VV);
                for (int vs = v0; vs < vend; vs += 64) {
                    int nv = vend - vs; if (nv > 64) nv = 64;
                    __syncthreads();
                    for (int i = t; i < 64*32; i += 256) {
                        int row = i >> 5, c4 = i & 31;
                        float4 val = make_float4(0.f,0.f,0.f,0.f);
                        if (row < nv) val = *(const float4*)(T2 + (size_t)(vs+row)*EE + c4*4);
                        *(float4*)(embS + row*128 + c4*4) = val;
                    }
                    for (int i = t; i < 512; i += 256) {
                        int b = i >> 4, vv4 = (i & 15)*4;
                        float4 val = make_float4(0.f,0.f,0.f,0.f);
                        if (vv4 < nv) val = *(const float4*)(a.w + (size_t)b*VV + vs + vv4);
                        wS[(vv4+0)*32 + b] = val.x;
                        wS[(vv4+1)*32 + b] = val.y;
                        wS[(vv4+2)*32 + b] = val.z;
                        wS[(vv4+3)*32 + b] = val.w;
                    }
                    __syncthreads();
                    for (int vv = 0; vv < nv; vv++) {
                        float2 ev = *(const float2*)(embS + vv*128 + lane*2);
                        float4 w0 = *(const float4*)(wS + vv*32 + wvid*8);
                        float4 w1 = *(const float4*)(wS + vv*32 + wvid*8 + 4);
                        av[0][0] += w0.x*ev.x; av[0][1] += w0.x*ev.y;
                        av[1][0] += w0.y*ev.x; av[1][1] += w0.y*ev.y;
                        av[2][0] += w0.z*ev.x; av[2][1] += w0.z*ev.y;
                        av[3][0] += w0.w*ev.x; av[3][1] += w0.w*ev.y;
                        av[4][0] += w1.x*ev.x; av[4][1] += w1.x*ev.y;
                        av[5][0] += w1.y*ev.x; av[5][1] += w1.y*ev.y;
                        av[6][0] += w1.z*ev.x; av[6][1] += w1.z*ev.y;
                        av[7][0] += w1.w*ev.x; av[7][1] += w1.w*ev.y;
                    }
                }
            }
            if (blk < NT) {
                #pragma unroll
                for (int j = 0; j < 8; j++) {
                    atomicAdd(a.o_acc + (wvid*8+j)*EE + lane*2,     av[j][0]);
                    atomicAdd(a.o_acc + (wvid*8+j)*EE + lane*2 + 1, av[j][1]);
                }
            }
            grid.sync();
        }
    }

    // ================= P4: vocab logits (K=256 wave-uniform GEMM) =================
    {
        float* Us = smem;          // [256][32]
        float* Wt = smem + 8192;   // [32][130]
        for (int tile = blk; tile < NT; tile += nb) {
            __syncthreads();
            for (int i = t; i < 256*32; i += 256) {
                int e = i >> 5, b = i & 31;
                Us[i] = (e < GG) ? a.q0[b*GG + e] : a.o1s[b*EE + (e - GG)];
            }
            int v0 = tile * 128;
            float acc[2][8];
            #pragma unroll
            for (int i = 0; i < 2; i++)
                #pragma unroll
                for (int j = 0; j < 8; j++) acc[i][j] = 0.f;

            for (int ec = 0; ec < 256; ec += 32) {
                __syncthreads();
                #pragma unroll
                for (int j = 0; j < 4; j++) {
                    int f = t + j*256;
                    int row = f >> 3, c4 = f & 7;
                    float4 w4 = make_float4(0.f,0.f,0.f,0.f);
                    if (v0 + row < VV) w4 = *(const float4*)(a.Wv + (size_t)(v0+row)*256 + ec + c4*4);
                    Wt[(c4*4+0)*130 + row] = w4.x;
                    Wt[(c4*4+1)*130 + row] = w4.y;
                    Wt[(c4*4+2)*130 + row] = w4.z;
                    Wt[(c4*4+3)*130 + row] = w4.w;
                }
                __syncthreads();
                #pragma unroll 8
                for (int e = 0; e < 32; e++) {
                    float2 w2 = *(const float2*)(Wt + e*130 + lane*2);
                    float4 ua = *(const float4*)(Us + (ec+e)*32 + wvid*8);
                    float4 ub = *(const float4*)(Us + (ec+e)*32 + wvid*8 + 4);
                    acc[0][0] += w2.x*ua.x; acc[1][0] += w2.y*ua.x;
                    acc[0][1] += w2.x*ua.y; acc[1][1] += w2.y*ua.y;
                    acc[0][2] += w2.x*ua.z; acc[1][2] += w2.y*ua.z;
                    acc[0][3] += w2.x*ua.w; acc[1][3] += w2.y*ua.w;
                    acc[0][4] += w2.x*ub.x; acc[1][4] += w2.y*ub.x;
                    acc[0][5] += w2.x*ub.y; acc[1][5] += w2.y*ub.y;
                    acc[0][6] += w2.x*ub.z; acc[1][6] += w2.y*ub.z;
                    acc[0][7] += w2.x*ub.w; acc[1][7] += w2.y*ub.w;
                }
            }
            int v = v0 + lane*2;
            if (v < VV) {
                float2 bb2 = *(const float2*)(a.bv + v);
                #pragma unroll
                for (int j = 0; j < 8; j++) {
                    float2 r; r.x = acc[0][j] + bb2.x; r.y = acc[1][j] + bb2.y;
                    *(float2*)(a.out_pv + (size_t)(wvid*8 + j)*VV + v) = r;
                }
            }
        }
    }
    grid.sync();

    // ================= P5: vocab softmax partials (blocks 0..255) =================
    if (blk < 256) {
        int b = blk >> 3, c = blk & 7;
        const float* row = a.out_pv + (size_t)b*VV;
        int start = c*6250, end = min(start + 6250, VV);
        float* red = smem;
        float mx = -INFINITY;
        for (int i = start + t; i < end; i += 256) mx = fmaxf(mx, row[i]);
        #pragma unroll
        for (int off = 32; off; off >>= 1) mx = fmaxf(mx, __shfl_down(mx, off));
        if (lane == 0) red[wvid] = mx;
        __syncthreads();
        float m = fmaxf(fmaxf(red[0], red[1]), fmaxf(red[2], red[3]));
        float sum = 0.f;
        for (int i = start + t; i < end; i += 256) sum += __expf(row[i] - m);
        #pragma unroll
        for (int off = 32; off; off >>= 1) sum += __shfl_down(sum, off);
        __syncthreads();
        if (lane == 0) red[8 + wvid] = sum;
        __syncthreads();
        if (t == 0) {
            a.part[blk*2]   = m;
            a.part[blk*2+1] = red[8]+red[9]+red[10]+red[11];
        }
    }
    grid.sync();

    // ================= P6: finalize p_vocab in place =================
    {
        float* Ms = smem;        // [32]
        float* Rs = smem + 32;   // [32]
        if (t < BB) {
            const float* pp = a.part + t*16;
            float M = -INFINITY;
            #pragma unroll
            for (int c = 0; c < 8; c++) M = fmaxf(M, pp[c*2]);
            float S = 0.f;
            #pragma unroll
            for (int c = 0; c < 8; c++) S += pp[c*2+1] * __expf(pp[c*2] - M);
            Ms[t] = M; Rs[t] = 1.f / S;
        }
        __syncthreads();
        const int total = BB*VV;
        for (int i = blk*256 + t; i < total; i += nb*256) {
            int b = i / VV;
            a.out_pv[i] = __expf(a.out_pv[i] - Ms[b]) * Rs[b];
        }
    }
}

extern "C" void kernel_launch(void* const* d_in, const int* in_sizes, int n_in,
                              void* d_out, int out_size, void* d_ws, size_t ws_size,
                              hipStream_t stream) {
    Args a;
    a.ctx   = (const int*)  d_in[0];
    a.hprev = (const float*)d_in[1];
    a.y     = (const int*)  d_in[2];
    a.emb   = (const float*)d_in[3];
    a.W_ih  = (const float*)d_in[4];
    a.W_hh  = (const float*)d_in[5];
    a.b_ih  = (const float*)d_in[6];
    a.b_hh  = (const float*)d_in[7];
    a.Wv    = (const float*)d_in[8];
    a.bv    = (const float*)d_in[9];

    float* out  = (float*)d_out;
    a.out_h     = out;                        // [B][G]
    a.out_pv    = out + BB*GG;                // [B][V]
    a.out_attn  = a.out_pv + (size_t)BB*VV;   // [B][M]

    float* ws = (float*)d_ws;
    a.q0    = ws;                             // 4096
    a.o1s   = a.q0 + BB*EE;                   // 4096
    a.part  = a.o1s + BB*EE;                  // 512
    a.d     = a.part + 512;                   // B*V
    a.w     = a.d + (size_t)BB*VV;            // B*V
    a.o_acc = a.w + (size_t)BB*VV;            // 4096 (contiguous after w for fused zeroing)

    int maxb = 0;
    int nb = 512;
    if (hipOccupancyMaxActiveBlocksPerMultiprocessor(&maxb, (const void*)fused_kernel, 256, 0) == hipSuccess
        && maxb >= 1) {
        nb = maxb * 256;            // 256 CUs on MI355X
        if (nb > 512) nb = 512;
        if (nb < 96)  nb = 96;      // phase logic floor (should not trigger)
    }
    a.nb = nb;

    void* params[] = { (void*)&a };
    hipLaunchCooperativeKernel((const void*)fused_kernel, dim3(nb), dim3(256),
                               params, 0, stream);
}